// Round 6
// baseline (14744.934 us; speedup 1.0000x reference)
//
#include <hip/hip_runtime.h>
#include <math.h>

#define T_SEQ 4096
#define H_DIM 1024
#define G4    4096
#define NBLK  128     // scan blocks; each owns 8 h-lanes (32 gate rows)
#define NTHR  256
// dynamic LDS: 64KB bf16 weights + 4KB h + 32 xg + 32 dot
#define SCAN_LDS_BYTES (65536 + 4096 + 128 + 128)

// ---------------------------------------------------------------------------
// K1: xg[t][j] = dot(embedding[tokens[t]], w_ih[j]) + b_ih[j] + b_hh[j]
// fp32 GEMM, 128x128 tile, BK=16, 256 threads, 8x8 microtile.
// ---------------------------------------------------------------------------
__global__ __launch_bounds__(256) void xg_gemm(
    const int* __restrict__ tokens, const float* __restrict__ emb,
    const float* __restrict__ w_ih, const float* __restrict__ b_ih,
    const float* __restrict__ b_hh, float* __restrict__ xg)
{
    __shared__ float As[16][128];
    __shared__ float Bs[16][128];
    __shared__ int   tk[128];

    const int tid  = threadIdx.x;
    const int row0 = blockIdx.y * 128;
    const int col0 = blockIdx.x * 128;

    if (tid < 128) tk[tid] = tokens[row0 + tid];
    __syncthreads();

    const int r    = tid >> 1;
    const int half = tid & 1;
    const int tx   = tid & 15;
    const int ty   = tid >> 4;

    const float* ap_base = emb + (size_t)tk[r] * 1024 + half * 8;
    const float* bp_base = w_ih + (size_t)(col0 + r) * 1024 + half * 8;

    float acc[8][8] = {};

    for (int kc = 0; kc < 1024; kc += 16) {
        const float4 a0 = ((const float4*)(ap_base + kc))[0];
        const float4 a1 = ((const float4*)(ap_base + kc))[1];
        const float4 b0 = ((const float4*)(bp_base + kc))[0];
        const float4 b1 = ((const float4*)(bp_base + kc))[1];
        __syncthreads();
        const int kb = half * 8;
        As[kb+0][r] = a0.x; As[kb+1][r] = a0.y; As[kb+2][r] = a0.z; As[kb+3][r] = a0.w;
        As[kb+4][r] = a1.x; As[kb+5][r] = a1.y; As[kb+6][r] = a1.z; As[kb+7][r] = a1.w;
        Bs[kb+0][r] = b0.x; Bs[kb+1][r] = b0.y; Bs[kb+2][r] = b0.z; Bs[kb+3][r] = b0.w;
        Bs[kb+4][r] = b1.x; Bs[kb+5][r] = b1.y; Bs[kb+6][r] = b1.z; Bs[kb+7][r] = b1.w;
        __syncthreads();
        #pragma unroll
        for (int k = 0; k < 16; ++k) {
            const float4 a0v = *(const float4*)&As[k][ty*8];
            const float4 a1v = *(const float4*)&As[k][ty*8+4];
            const float4 b0v = *(const float4*)&Bs[k][tx*8];
            const float4 b1v = *(const float4*)&Bs[k][tx*8+4];
            const float aa[8] = {a0v.x,a0v.y,a0v.z,a0v.w,a1v.x,a1v.y,a1v.z,a1v.w};
            const float bb[8] = {b0v.x,b0v.y,b0v.z,b0v.w,b1v.x,b1v.y,b1v.z,b1v.w};
            #pragma unroll
            for (int ii = 0; ii < 8; ++ii)
                #pragma unroll
                for (int jj = 0; jj < 8; ++jj)
                    acc[ii][jj] = fmaf(aa[ii], bb[jj], acc[ii][jj]);
        }
    }

    const int ccol = col0 + tx * 8;
    float bs[8];
    #pragma unroll
    for (int jj = 0; jj < 8; ++jj) bs[jj] = b_ih[ccol + jj] + b_hh[ccol + jj];
    #pragma unroll
    for (int ii = 0; ii < 8; ++ii) {
        float* orow = xg + (size_t)(row0 + ty*8 + ii) * G4 + ccol;
        float4 o0, o1;
        o0.x = acc[ii][0] + bs[0]; o0.y = acc[ii][1] + bs[1];
        o0.z = acc[ii][2] + bs[2]; o0.w = acc[ii][3] + bs[3];
        o1.x = acc[ii][4] + bs[4]; o1.y = acc[ii][5] + bs[5];
        o1.z = acc[ii][6] + bs[6]; o1.w = acc[ii][7] + bs[7];
        ((float4*)orow)[0] = o0;
        ((float4*)orow)[1] = o1;
    }
}

// ---------------------------------------------------------------------------
// K2: persistent LSTM scan.  128 blocks x 256 threads; block b owns h-lanes
// {8b..8b+7} (32 gate rows).  Weights: bf16 in LDS (64 KB/block), staged
// once, stored wave-interleaved [wave][i][lane] in 16B chunks so every
// per-step ds_read_b128 is lane-consecutive (the canonical conflict-free
// pattern).  R5 showed the per-step 256KB L2 weight stream (64 B/clk/CU =
// 1.7us) was the critical path; LDS residency removes it.  h fp32 in LDS,
// read 8-lane-broadcast.  Cross-block h exchange: 8-byte relaxed agent
// atomics {ver,bits}; no fences.  2-slot ring, max skew 1 step.
// ---------------------------------------------------------------------------
__device__ __forceinline__ float fsigmoid_(float x) {
    return 1.0f / (1.0f + __expf(-x));
}
__device__ __forceinline__ float ftanh_(float x) {
    x = fminf(fmaxf(x, -10.0f), 10.0f);
    const float e = __expf(2.0f * x);
    return (e - 1.0f) / (e + 1.0f);
}
__device__ __forceinline__ unsigned bf16rne_(float f) {   // finite inputs
    const unsigned u = __float_as_uint(f);
    return (u + 0x7FFFu + ((u >> 16) & 1u)) >> 16;
}
__device__ __forceinline__ float bf_lo_(unsigned u) {
    return __uint_as_float(u << 16);
}
__device__ __forceinline__ float bf_hi_(unsigned u) {
    return __uint_as_float(u & 0xFFFF0000u);
}

__global__ __launch_bounds__(NTHR, 1) void lstm_scan(
    const float* __restrict__ xg, const float* __restrict__ w_hh,
    const float* __restrict__ h0, const float* __restrict__ c0,
    unsigned long long* h_msg,           // [2][1024] {tag,bits}
    float* __restrict__ h_fin, float* __restrict__ c_fin)
{
    extern __shared__ char smem[];
    unsigned* w_lds   = (unsigned*)smem;            // 16384 u32 (32 rows bf16)
    float*    h_lds   = (float*)(smem + 65536);     // 1024 f32
    float*    xg_lds  = h_lds + H_DIM;              // 32
    float*    dot_lds = xg_lds + 32;                // 32

    const int tid  = threadIdx.x;
    const int b    = blockIdx.x;
    const int lane = tid & 63;
    const int wv   = tid >> 6;           // wave 0..3
    const int r    = tid >> 3;           // gate-row within block 0..31
    const int j    = tid & 7;            // k-slice (128 floats)
    const int g    = r >> 3;             // gate 0..3
    const int m    = r & 7;              // h-lane within block
    const int grow = g * 1024 + 8 * b + m;

    // ---- stage weights: fp32 global -> bf16 packed, wave-interleaved layout
    {
        const float* wsrc = w_hh + (size_t)grow * 1024 + j * 128;
        uint4* wdst = (uint4*)w_lds + (size_t)wv * 16 * 64 + lane;
        #pragma unroll
        for (int i = 0; i < 16; ++i) {
            const float4 a = ((const float4*)(wsrc + i * 8))[0];
            const float4 c = ((const float4*)(wsrc + i * 8))[1];
            uint4 u;
            u.x = bf16rne_(a.x) | (bf16rne_(a.y) << 16);
            u.y = bf16rne_(a.z) | (bf16rne_(a.w) << 16);
            u.z = bf16rne_(c.x) | (bf16rne_(c.y) << 16);
            u.w = bf16rne_(c.z) | (bf16rne_(c.w) << 16);
            wdst[i * 64] = u;
        }
    }

    float c_reg = 0.0f;
    if (tid < 8) c_reg = c0[8 * b + tid];

    // h version 0 from h0
    ((float4*)h_lds)[tid] = ((const float4*)h0)[tid];

    // prefetch xg for t=0 (tid<32 owns (gate=tid>>3, lane m=tid&7))
    float xc = 0.0f;
    if (tid < 32)
        xc = xg[(size_t)(tid >> 3) * 1024 + 8 * b + (tid & 7)];
    __syncthreads();

    const uint4*  wrd = (const uint4*)w_lds + (size_t)wv * 16 * 64 + lane;
    const float4* h4  = (const float4*)h_lds + j * 32;

    for (int t = 0; t < T_SEQ; ++t) {
        // stage this step's xg into LDS; issue next step's prefetch
        if (tid < 32) {
            xg_lds[tid] = xc;
            if (t < T_SEQ - 1)
                xc = xg[(size_t)(t + 1) * G4 + (tid >> 3) * 1024 + 8 * b + (tid & 7)];
        }

        // 128-MAC partial dot: bf16 weights (LDS, lane-consecutive b128) x
        // fp32 h (LDS, 8-lane broadcast)
        float acc = 0.0f;
        #pragma unroll
        for (int i = 0; i < 16; ++i) {
            const uint4  u  = wrd[i * 64];
            const float4 ha = h4[i * 2];
            const float4 hb = h4[i * 2 + 1];
            acc = fmaf(bf_lo_(u.x), ha.x, acc);
            acc = fmaf(bf_hi_(u.x), ha.y, acc);
            acc = fmaf(bf_lo_(u.y), ha.z, acc);
            acc = fmaf(bf_hi_(u.y), ha.w, acc);
            acc = fmaf(bf_lo_(u.z), hb.x, acc);
            acc = fmaf(bf_hi_(u.z), hb.y, acc);
            acc = fmaf(bf_lo_(u.w), hb.z, acc);
            acc = fmaf(bf_hi_(u.w), hb.w, acc);
        }
        acc += __shfl_xor(acc, 1);
        acc += __shfl_xor(acc, 2);
        acc += __shfl_xor(acc, 4);
        if (j == 0) dot_lds[r] = acc;
        __syncthreads();

        // pointwise update + publish (8 threads; rest proceed to their polls)
        if (tid < 8) {
            const float gi = xg_lds[tid]      + dot_lds[tid];
            const float gf = xg_lds[8 + tid]  + dot_lds[8 + tid];
            const float gg = xg_lds[16 + tid] + dot_lds[16 + tid];
            const float go = xg_lds[24 + tid] + dot_lds[24 + tid];
            const float ii = fsigmoid_(gi);
            const float ff = fsigmoid_(gf);
            const float gt = ftanh_(gg);
            const float oo = fsigmoid_(go);
            c_reg = ff * c_reg + ii * gt;
            const float hn = oo * ftanh_(c_reg);
            const unsigned long long msg =
                ((unsigned long long)(unsigned)(t + 1) << 32) | __float_as_uint(hn);
            __hip_atomic_store(&h_msg[(size_t)((t + 1) & 1) * H_DIM + 8 * b + tid],
                               msg, __ATOMIC_RELAXED, __HIP_MEMORY_SCOPE_AGENT);
            if (t == T_SEQ - 1) {
                h_fin[8 * b + tid] = hn;
                c_fin[8 * b + tid] = c_reg;
            }
        }

        // gather h version t+1: each thread polls only its own 4 messages
        // (wave reads 2 KB contiguous -> coalesced)
        if (t < T_SEQ - 1) {
            const unsigned ver = (unsigned)(t + 1);
            const unsigned long long* src =
                h_msg + (size_t)(ver & 1) * H_DIM + 4 * tid;
            unsigned long long v0, v1, v2, v3;
            for (;;) {
                v0 = __hip_atomic_load(src + 0, __ATOMIC_RELAXED, __HIP_MEMORY_SCOPE_AGENT);
                v1 = __hip_atomic_load(src + 1, __ATOMIC_RELAXED, __HIP_MEMORY_SCOPE_AGENT);
                v2 = __hip_atomic_load(src + 2, __ATOMIC_RELAXED, __HIP_MEMORY_SCOPE_AGENT);
                v3 = __hip_atomic_load(src + 3, __ATOMIC_RELAXED, __HIP_MEMORY_SCOPE_AGENT);
                if (((unsigned)(v0 >> 32) == ver) & ((unsigned)(v1 >> 32) == ver) &
                    ((unsigned)(v2 >> 32) == ver) & ((unsigned)(v3 >> 32) == ver))
                    break;
            }
            float4 hv;
            hv.x = __uint_as_float((unsigned)v0);
            hv.y = __uint_as_float((unsigned)v1);
            hv.z = __uint_as_float((unsigned)v2);
            hv.w = __uint_as_float((unsigned)v3);
            ((float4*)h_lds)[tid] = hv;
            __syncthreads();
        }
    }
}

// ---------------------------------------------------------------------------
// K3: four 256x1024 mat-vec projections + bias.  One output per 32-lane group.
// ---------------------------------------------------------------------------
__global__ __launch_bounds__(256) void proj_kernel(
    const float* __restrict__ h_fin, const float* __restrict__ c_fin,
    const float* __restrict__ W_hm, const float* __restrict__ b_hm,
    const float* __restrict__ W_hv, const float* __restrict__ b_hv,
    const float* __restrict__ W_cm, const float* __restrict__ b_cm,
    const float* __restrict__ W_cv, const float* __restrict__ b_cv,
    float* __restrict__ out)
{
    const int tid = threadIdx.x;
    const int g32 = tid >> 5;
    const int j   = tid & 31;
    const int o   = blockIdx.x * 8 + g32;   // 0..1023
    const int mat = o >> 8;
    const int l   = o & 255;

    const float* W;  const float* bias;  const float* vec;
    if      (mat == 0) { W = W_hm; bias = b_hm; vec = h_fin; }
    else if (mat == 1) { W = W_hv; bias = b_hv; vec = h_fin; }
    else if (mat == 2) { W = W_cm; bias = b_cm; vec = c_fin; }
    else               { W = W_cv; bias = b_cv; vec = c_fin; }

    const float* wrow = W + (size_t)l * 1024;
    float acc = 0.0f;
    #pragma unroll
    for (int i = 0; i < 8; ++i) {
        const float4 wv = *(const float4*)(wrow + i * 128 + j * 4);
        const float4 xv = *(const float4*)(vec  + i * 128 + j * 4);
        acc += wv.x * xv.x + wv.y * xv.y + wv.z * xv.z + wv.w * xv.w;
    }
    acc += __shfl_xor(acc, 1);
    acc += __shfl_xor(acc, 2);
    acc += __shfl_xor(acc, 4);
    acc += __shfl_xor(acc, 8);
    acc += __shfl_xor(acc, 16);
    if (j == 0) out[o] = acc + bias[l];
}

// ---------------------------------------------------------------------------
extern "C" void kernel_launch(void* const* d_in, const int* in_sizes, int n_in,
                              void* d_out, int out_size, void* d_ws, size_t ws_size,
                              hipStream_t stream)
{
    const int*   tokens = (const int*)  d_in[0];
    const float* h0     = (const float*)d_in[1];
    const float* c0     = (const float*)d_in[2];
    const float* emb    = (const float*)d_in[3];
    const float* w_ih   = (const float*)d_in[4];
    const float* w_hh   = (const float*)d_in[5];
    const float* b_ih   = (const float*)d_in[6];
    const float* b_hh   = (const float*)d_in[7];
    const float* W_hm   = (const float*)d_in[8];
    const float* b_hm   = (const float*)d_in[9];
    const float* W_hv   = (const float*)d_in[10];
    const float* b_hv   = (const float*)d_in[11];
    const float* W_cm   = (const float*)d_in[12];
    const float* b_cm   = (const float*)d_in[13];
    const float* W_cv   = (const float*)d_in[14];
    const float* b_cv   = (const float*)d_in[15];
    float* out = (float*)d_out;

    char* ws = (char*)d_ws;
    float*              xg    = (float*)ws;            // T*4H fp32 = 64 MB
    size_t              off   = (size_t)T_SEQ * G4 * sizeof(float);
    unsigned long long* h_msg = (unsigned long long*)(ws + off);
    off += 2 * H_DIM * sizeof(unsigned long long);     // 16 KB
    float* h_fin = (float*)(ws + off); off += H_DIM * sizeof(float);
    float* c_fin = (float*)(ws + off); off += H_DIM * sizeof(float);

    // allow 69.9 KB dynamic LDS for the scan kernel (host attr, capture-safe)
    hipFuncSetAttribute((const void*)lstm_scan,
                        hipFuncAttributeMaxDynamicSharedMemorySize,
                        SCAN_LDS_BYTES);

    // clear stale tags (part of the captured graph => replay-safe)
    hipMemsetAsync(h_msg, 0xFF, 2 * H_DIM * sizeof(unsigned long long), stream);

    xg_gemm<<<dim3(32, 32), 256, 0, stream>>>(tokens, emb, w_ih, b_ih, b_hh, xg);
    lstm_scan<<<NBLK, NTHR, SCAN_LDS_BYTES, stream>>>(xg, w_hh, h0, c0, h_msg,
                                                      h_fin, c_fin);
    proj_kernel<<<128, 256, 0, stream>>>(h_fin, c_fin, W_hm, b_hm, W_hv, b_hv,
                                         W_cm, b_cm, W_cv, b_cv, out);
}

// Round 7
// 10447.249 us; speedup vs baseline: 1.4114x; 1.4114x over previous
//
#include <hip/hip_runtime.h>
#include <math.h>

#define T_SEQ 4096
#define H_DIM 1024
#define G4    4096
#define NBLK  128     // scan blocks; each owns 8 h-lanes (32 gate rows)
#define NTHR  256
// dynamic LDS: 64KB bf16 weights + 4KB h + 32 xg + 32 dot
#define SCAN_LDS_BYTES (65536 + 4096 + 128 + 128)

// ---------------------------------------------------------------------------
// K1: xg[t][j] = dot(embedding[tokens[t]], w_ih[j]) + b_ih[j] + b_hh[j]
// fp32 GEMM, 128x128 tile, BK=16, 256 threads, 8x8 microtile.
// ---------------------------------------------------------------------------
__global__ __launch_bounds__(256) void xg_gemm(
    const int* __restrict__ tokens, const float* __restrict__ emb,
    const float* __restrict__ w_ih, const float* __restrict__ b_ih,
    const float* __restrict__ b_hh, float* __restrict__ xg)
{
    __shared__ float As[16][128];
    __shared__ float Bs[16][128];
    __shared__ int   tk[128];

    const int tid  = threadIdx.x;
    const int row0 = blockIdx.y * 128;
    const int col0 = blockIdx.x * 128;

    if (tid < 128) tk[tid] = tokens[row0 + tid];
    __syncthreads();

    const int r    = tid >> 1;
    const int half = tid & 1;
    const int tx   = tid & 15;
    const int ty   = tid >> 4;

    const float* ap_base = emb + (size_t)tk[r] * 1024 + half * 8;
    const float* bp_base = w_ih + (size_t)(col0 + r) * 1024 + half * 8;

    float acc[8][8] = {};

    for (int kc = 0; kc < 1024; kc += 16) {
        const float4 a0 = ((const float4*)(ap_base + kc))[0];
        const float4 a1 = ((const float4*)(ap_base + kc))[1];
        const float4 b0 = ((const float4*)(bp_base + kc))[0];
        const float4 b1 = ((const float4*)(bp_base + kc))[1];
        __syncthreads();
        const int kb = half * 8;
        As[kb+0][r] = a0.x; As[kb+1][r] = a0.y; As[kb+2][r] = a0.z; As[kb+3][r] = a0.w;
        As[kb+4][r] = a1.x; As[kb+5][r] = a1.y; As[kb+6][r] = a1.z; As[kb+7][r] = a1.w;
        Bs[kb+0][r] = b0.x; Bs[kb+1][r] = b0.y; Bs[kb+2][r] = b0.z; Bs[kb+3][r] = b0.w;
        Bs[kb+4][r] = b1.x; Bs[kb+5][r] = b1.y; Bs[kb+6][r] = b1.z; Bs[kb+7][r] = b1.w;
        __syncthreads();
        #pragma unroll
        for (int k = 0; k < 16; ++k) {
            const float4 a0v = *(const float4*)&As[k][ty*8];
            const float4 a1v = *(const float4*)&As[k][ty*8+4];
            const float4 b0v = *(const float4*)&Bs[k][tx*8];
            const float4 b1v = *(const float4*)&Bs[k][tx*8+4];
            const float aa[8] = {a0v.x,a0v.y,a0v.z,a0v.w,a1v.x,a1v.y,a1v.z,a1v.w};
            const float bb[8] = {b0v.x,b0v.y,b0v.z,b0v.w,b1v.x,b1v.y,b1v.z,b1v.w};
            #pragma unroll
            for (int ii = 0; ii < 8; ++ii)
                #pragma unroll
                for (int jj = 0; jj < 8; ++jj)
                    acc[ii][jj] = fmaf(aa[ii], bb[jj], acc[ii][jj]);
        }
    }

    const int ccol = col0 + tx * 8;
    float bs[8];
    #pragma unroll
    for (int jj = 0; jj < 8; ++jj) bs[jj] = b_ih[ccol + jj] + b_hh[ccol + jj];
    #pragma unroll
    for (int ii = 0; ii < 8; ++ii) {
        float* orow = xg + (size_t)(row0 + ty*8 + ii) * G4 + ccol;
        float4 o0, o1;
        o0.x = acc[ii][0] + bs[0]; o0.y = acc[ii][1] + bs[1];
        o0.z = acc[ii][2] + bs[2]; o0.w = acc[ii][3] + bs[3];
        o1.x = acc[ii][4] + bs[4]; o1.y = acc[ii][5] + bs[5];
        o1.z = acc[ii][6] + bs[6]; o1.w = acc[ii][7] + bs[7];
        ((float4*)orow)[0] = o0;
        ((float4*)orow)[1] = o1;
    }
}

// ---------------------------------------------------------------------------
// K2: persistent LSTM scan.  128 blocks x 256 threads; block b owns h-lanes
// {8b..8b+7} (32 gate rows).  Weights bf16 in LDS (64 KB/block), staged once.
// R6 lesson (SQ_LDS_BANK_CONFLICT=1.9e9): h-slice reads at 512B stride are an
// 8-way bank conflict.  Fix: rotate at STAGING (LDS slot i of a thread holds
// its global chunk c=(i+j)&15), so per-step weight reads stay lane-consecutive
// (canonical conflict-free b128) while h reads become 512j+32*((i+j)&15) =>
// bank quad 8*((i+j)%4) => 2-way max, which is free (m136).
// Cross-block h exchange: 8-byte relaxed agent atomics {ver,bits}; no fences.
// 2-slot ring, max skew 1 step.
// ---------------------------------------------------------------------------
__device__ __forceinline__ float fsigmoid_(float x) {
    return 1.0f / (1.0f + __expf(-x));
}
__device__ __forceinline__ float ftanh_(float x) {
    x = fminf(fmaxf(x, -10.0f), 10.0f);
    const float e = __expf(2.0f * x);
    return (e - 1.0f) / (e + 1.0f);
}
__device__ __forceinline__ unsigned bf16rne_(float f) {   // finite inputs
    const unsigned u = __float_as_uint(f);
    return (u + 0x7FFFu + ((u >> 16) & 1u)) >> 16;
}
__device__ __forceinline__ float bf_lo_(unsigned u) {
    return __uint_as_float(u << 16);
}
__device__ __forceinline__ float bf_hi_(unsigned u) {
    return __uint_as_float(u & 0xFFFF0000u);
}

__global__ __launch_bounds__(NTHR, 1) void lstm_scan(
    const float* __restrict__ xg, const float* __restrict__ w_hh,
    const float* __restrict__ h0, const float* __restrict__ c0,
    unsigned long long* h_msg,           // [2][1024] {tag,bits}
    float* __restrict__ h_fin, float* __restrict__ c_fin)
{
    extern __shared__ char smem[];
    unsigned* w_lds   = (unsigned*)smem;            // 16384 u32 (32 rows bf16)
    float*    h_lds   = (float*)(smem + 65536);     // 1024 f32
    float*    xg_lds  = h_lds + H_DIM;              // 32
    float*    dot_lds = xg_lds + 32;                // 32

    const int tid  = threadIdx.x;
    const int b    = blockIdx.x;
    const int lane = tid & 63;
    const int wv   = tid >> 6;           // wave 0..3
    const int r    = tid >> 3;           // gate-row within block 0..31
    const int j    = tid & 7;            // k-slice (128 floats)
    const int g    = r >> 3;             // gate 0..3
    const int m    = r & 7;              // h-lane within block
    const int grow = g * 1024 + 8 * b + m;

    // ---- stage weights: fp32 global -> bf16 packed; slot i holds global
    // chunk c=(i+j)&15 (rotation baked into storage, see header comment)
    {
        const float* wsrc = w_hh + (size_t)grow * 1024 + j * 128;
        uint4* wdst = (uint4*)w_lds + (size_t)wv * 16 * 64 + lane;
        #pragma unroll
        for (int i = 0; i < 16; ++i) {
            const int c = (i + j) & 15;
            const float4 a = ((const float4*)(wsrc + c * 8))[0];
            const float4 d = ((const float4*)(wsrc + c * 8))[1];
            uint4 u;
            u.x = bf16rne_(a.x) | (bf16rne_(a.y) << 16);
            u.y = bf16rne_(a.z) | (bf16rne_(a.w) << 16);
            u.z = bf16rne_(d.x) | (bf16rne_(d.y) << 16);
            u.w = bf16rne_(d.z) | (bf16rne_(d.w) << 16);
            wdst[i * 64] = u;
        }
    }

    float c_reg = 0.0f;
    if (tid < 8) c_reg = c0[8 * b + tid];

    // h version 0 from h0
    ((float4*)h_lds)[tid] = ((const float4*)h0)[tid];

    // prefetch xg for t=0 (tid<32 owns (gate=tid>>3, lane m=tid&7))
    float xc = 0.0f;
    if (tid < 32)
        xc = xg[(size_t)(tid >> 3) * 1024 + 8 * b + (tid & 7)];
    __syncthreads();

    const uint4*  wrd = (const uint4*)w_lds + (size_t)wv * 16 * 64 + lane;
    const float4* h4  = (const float4*)h_lds + j * 32;

    for (int t = 0; t < T_SEQ; ++t) {
        // stage this step's xg into LDS; issue next step's prefetch
        if (tid < 32) {
            xg_lds[tid] = xc;
            if (t < T_SEQ - 1)
                xc = xg[(size_t)(t + 1) * G4 + (tid >> 3) * 1024 + 8 * b + (tid & 7)];
        }

        // 128-MAC partial dot: bf16 weights (LDS, lane-consecutive b128) x
        // fp32 h (LDS, bank-staggered via staged rotation; 2-way max = free)
        float acc = 0.0f;
        #pragma unroll
        for (int i = 0; i < 16; ++i) {
            const int c = (i + j) & 15;
            const uint4  u  = wrd[i * 64];
            const float4 ha = h4[2 * c];
            const float4 hb = h4[2 * c + 1];
            acc = fmaf(bf_lo_(u.x), ha.x, acc);
            acc = fmaf(bf_hi_(u.x), ha.y, acc);
            acc = fmaf(bf_lo_(u.y), ha.z, acc);
            acc = fmaf(bf_hi_(u.y), ha.w, acc);
            acc = fmaf(bf_lo_(u.z), hb.x, acc);
            acc = fmaf(bf_hi_(u.z), hb.y, acc);
            acc = fmaf(bf_lo_(u.w), hb.z, acc);
            acc = fmaf(bf_hi_(u.w), hb.w, acc);
        }
        acc += __shfl_xor(acc, 1);
        acc += __shfl_xor(acc, 2);
        acc += __shfl_xor(acc, 4);
        if (j == 0) dot_lds[r] = acc;
        __syncthreads();

        // pointwise update + publish (8 threads; rest proceed to their polls)
        if (tid < 8) {
            const float gi = xg_lds[tid]      + dot_lds[tid];
            const float gf = xg_lds[8 + tid]  + dot_lds[8 + tid];
            const float gg = xg_lds[16 + tid] + dot_lds[16 + tid];
            const float go = xg_lds[24 + tid] + dot_lds[24 + tid];
            const float ii = fsigmoid_(gi);
            const float ff = fsigmoid_(gf);
            const float gt = ftanh_(gg);
            const float oo = fsigmoid_(go);
            c_reg = ff * c_reg + ii * gt;
            const float hn = oo * ftanh_(c_reg);
            const unsigned long long msg =
                ((unsigned long long)(unsigned)(t + 1) << 32) | __float_as_uint(hn);
            __hip_atomic_store(&h_msg[(size_t)((t + 1) & 1) * H_DIM + 8 * b + tid],
                               msg, __ATOMIC_RELAXED, __HIP_MEMORY_SCOPE_AGENT);
            if (t == T_SEQ - 1) {
                h_fin[8 * b + tid] = hn;
                c_fin[8 * b + tid] = c_reg;
            }
        }

        // gather h version t+1: each thread polls only its own 4 messages
        // (wave reads 2 KB contiguous -> coalesced)
        if (t < T_SEQ - 1) {
            const unsigned ver = (unsigned)(t + 1);
            const unsigned long long* src =
                h_msg + (size_t)(ver & 1) * H_DIM + 4 * tid;
            unsigned long long v0, v1, v2, v3;
            for (;;) {
                v0 = __hip_atomic_load(src + 0, __ATOMIC_RELAXED, __HIP_MEMORY_SCOPE_AGENT);
                v1 = __hip_atomic_load(src + 1, __ATOMIC_RELAXED, __HIP_MEMORY_SCOPE_AGENT);
                v2 = __hip_atomic_load(src + 2, __ATOMIC_RELAXED, __HIP_MEMORY_SCOPE_AGENT);
                v3 = __hip_atomic_load(src + 3, __ATOMIC_RELAXED, __HIP_MEMORY_SCOPE_AGENT);
                if (((unsigned)(v0 >> 32) == ver) & ((unsigned)(v1 >> 32) == ver) &
                    ((unsigned)(v2 >> 32) == ver) & ((unsigned)(v3 >> 32) == ver))
                    break;
            }
            float4 hv;
            hv.x = __uint_as_float((unsigned)v0);
            hv.y = __uint_as_float((unsigned)v1);
            hv.z = __uint_as_float((unsigned)v2);
            hv.w = __uint_as_float((unsigned)v3);
            ((float4*)h_lds)[tid] = hv;
            __syncthreads();
        }
    }
}

// ---------------------------------------------------------------------------
// K3: four 256x1024 mat-vec projections + bias.  One output per 32-lane group.
// ---------------------------------------------------------------------------
__global__ __launch_bounds__(256) void proj_kernel(
    const float* __restrict__ h_fin, const float* __restrict__ c_fin,
    const float* __restrict__ W_hm, const float* __restrict__ b_hm,
    const float* __restrict__ W_hv, const float* __restrict__ b_hv,
    const float* __restrict__ W_cm, const float* __restrict__ b_cm,
    const float* __restrict__ W_cv, const float* __restrict__ b_cv,
    float* __restrict__ out)
{
    const int tid = threadIdx.x;
    const int g32 = tid >> 5;
    const int j   = tid & 31;
    const int o   = blockIdx.x * 8 + g32;   // 0..1023
    const int mat = o >> 8;
    const int l   = o & 255;

    const float* W;  const float* bias;  const float* vec;
    if      (mat == 0) { W = W_hm; bias = b_hm; vec = h_fin; }
    else if (mat == 1) { W = W_hv; bias = b_hv; vec = h_fin; }
    else if (mat == 2) { W = W_cm; bias = b_cm; vec = c_fin; }
    else               { W = W_cv; bias = b_cv; vec = c_fin; }

    const float* wrow = W + (size_t)l * 1024;
    float acc = 0.0f;
    #pragma unroll
    for (int i = 0; i < 8; ++i) {
        const float4 wv = *(const float4*)(wrow + i * 128 + j * 4);
        const float4 xv = *(const float4*)(vec  + i * 128 + j * 4);
        acc += wv.x * xv.x + wv.y * xv.y + wv.z * xv.z + wv.w * xv.w;
    }
    acc += __shfl_xor(acc, 1);
    acc += __shfl_xor(acc, 2);
    acc += __shfl_xor(acc, 4);
    acc += __shfl_xor(acc, 8);
    acc += __shfl_xor(acc, 16);
    if (j == 0) out[o] = acc + bias[l];
}

// ---------------------------------------------------------------------------
extern "C" void kernel_launch(void* const* d_in, const int* in_sizes, int n_in,
                              void* d_out, int out_size, void* d_ws, size_t ws_size,
                              hipStream_t stream)
{
    const int*   tokens = (const int*)  d_in[0];
    const float* h0     = (const float*)d_in[1];
    const float* c0     = (const float*)d_in[2];
    const float* emb    = (const float*)d_in[3];
    const float* w_ih   = (const float*)d_in[4];
    const float* w_hh   = (const float*)d_in[5];
    const float* b_ih   = (const float*)d_in[6];
    const float* b_hh   = (const float*)d_in[7];
    const float* W_hm   = (const float*)d_in[8];
    const float* b_hm   = (const float*)d_in[9];
    const float* W_hv   = (const float*)d_in[10];
    const float* b_hv   = (const float*)d_in[11];
    const float* W_cm   = (const float*)d_in[12];
    const float* b_cm   = (const float*)d_in[13];
    const float* W_cv   = (const float*)d_in[14];
    const float* b_cv   = (const float*)d_in[15];
    float* out = (float*)d_out;

    char* ws = (char*)d_ws;
    float*              xg    = (float*)ws;            // T*4H fp32 = 64 MB
    size_t              off   = (size_t)T_SEQ * G4 * sizeof(float);
    unsigned long long* h_msg = (unsigned long long*)(ws + off);
    off += 2 * H_DIM * sizeof(unsigned long long);     // 16 KB
    float* h_fin = (float*)(ws + off); off += H_DIM * sizeof(float);
    float* c_fin = (float*)(ws + off); off += H_DIM * sizeof(float);

    // allow 69.9 KB dynamic LDS for the scan kernel (host attr, capture-safe)
    hipFuncSetAttribute((const void*)lstm_scan,
                        hipFuncAttributeMaxDynamicSharedMemorySize,
                        SCAN_LDS_BYTES);

    // clear stale tags (part of the captured graph => replay-safe)
    hipMemsetAsync(h_msg, 0xFF, 2 * H_DIM * sizeof(unsigned long long), stream);

    xg_gemm<<<dim3(32, 32), 256, 0, stream>>>(tokens, emb, w_ih, b_ih, b_hh, xg);
    lstm_scan<<<NBLK, NTHR, SCAN_LDS_BYTES, stream>>>(xg, w_hh, h0, c0, h_msg,
                                                      h_fin, c_fin);
    proj_kernel<<<128, 256, 0, stream>>>(h_fin, c_fin, W_hm, b_hm, W_hv, b_hv,
                                         W_cm, b_cm, W_cv, b_cv, out);
}

// Round 8
// 9126.591 us; speedup vs baseline: 1.6156x; 1.1447x over previous
//
#include <hip/hip_runtime.h>
#include <math.h>

#define T_SEQ 4096
#define H_DIM 1024
#define G4    4096
#define NBLK  64      // scan blocks; each owns 16 h-lanes (64 gate rows)
#define NTHR  512
// dynamic LDS: 128KB bf16 weights + 4KB h + 256B xg + 256B dot
#define SCAN_LDS_BYTES (131072 + 4096 + 256 + 256)

// ---------------------------------------------------------------------------
// K1: xg[t][j] = dot(embedding[tokens[t]], w_ih[j]) + b_ih[j] + b_hh[j]
// fp32 GEMM, 128x128 tile, BK=16, 256 threads, 8x8 microtile.
// ---------------------------------------------------------------------------
__global__ __launch_bounds__(256) void xg_gemm(
    const int* __restrict__ tokens, const float* __restrict__ emb,
    const float* __restrict__ w_ih, const float* __restrict__ b_ih,
    const float* __restrict__ b_hh, float* __restrict__ xg)
{
    __shared__ float As[16][128];
    __shared__ float Bs[16][128];
    __shared__ int   tk[128];

    const int tid  = threadIdx.x;
    const int row0 = blockIdx.y * 128;
    const int col0 = blockIdx.x * 128;

    if (tid < 128) tk[tid] = tokens[row0 + tid];
    __syncthreads();

    const int r    = tid >> 1;
    const int half = tid & 1;
    const int tx   = tid & 15;
    const int ty   = tid >> 4;

    const float* ap_base = emb + (size_t)tk[r] * 1024 + half * 8;
    const float* bp_base = w_ih + (size_t)(col0 + r) * 1024 + half * 8;

    float acc[8][8] = {};

    for (int kc = 0; kc < 1024; kc += 16) {
        const float4 a0 = ((const float4*)(ap_base + kc))[0];
        const float4 a1 = ((const float4*)(ap_base + kc))[1];
        const float4 b0 = ((const float4*)(bp_base + kc))[0];
        const float4 b1 = ((const float4*)(bp_base + kc))[1];
        __syncthreads();
        const int kb = half * 8;
        As[kb+0][r] = a0.x; As[kb+1][r] = a0.y; As[kb+2][r] = a0.z; As[kb+3][r] = a0.w;
        As[kb+4][r] = a1.x; As[kb+5][r] = a1.y; As[kb+6][r] = a1.z; As[kb+7][r] = a1.w;
        Bs[kb+0][r] = b0.x; Bs[kb+1][r] = b0.y; Bs[kb+2][r] = b0.z; Bs[kb+3][r] = b0.w;
        Bs[kb+4][r] = b1.x; Bs[kb+5][r] = b1.y; Bs[kb+6][r] = b1.z; Bs[kb+7][r] = b1.w;
        __syncthreads();
        #pragma unroll
        for (int k = 0; k < 16; ++k) {
            const float4 a0v = *(const float4*)&As[k][ty*8];
            const float4 a1v = *(const float4*)&As[k][ty*8+4];
            const float4 b0v = *(const float4*)&Bs[k][tx*8];
            const float4 b1v = *(const float4*)&Bs[k][tx*8+4];
            const float aa[8] = {a0v.x,a0v.y,a0v.z,a0v.w,a1v.x,a1v.y,a1v.z,a1v.w};
            const float bb[8] = {b0v.x,b0v.y,b0v.z,b0v.w,b1v.x,b1v.y,b1v.z,b1v.w};
            #pragma unroll
            for (int ii = 0; ii < 8; ++ii)
                #pragma unroll
                for (int jj = 0; jj < 8; ++jj)
                    acc[ii][jj] = fmaf(aa[ii], bb[jj], acc[ii][jj]);
        }
    }

    const int ccol = col0 + tx * 8;
    float bs[8];
    #pragma unroll
    for (int jj = 0; jj < 8; ++jj) bs[jj] = b_ih[ccol + jj] + b_hh[ccol + jj];
    #pragma unroll
    for (int ii = 0; ii < 8; ++ii) {
        float* orow = xg + (size_t)(row0 + ty*8 + ii) * G4 + ccol;
        float4 o0, o1;
        o0.x = acc[ii][0] + bs[0]; o0.y = acc[ii][1] + bs[1];
        o0.z = acc[ii][2] + bs[2]; o0.w = acc[ii][3] + bs[3];
        o1.x = acc[ii][4] + bs[4]; o1.y = acc[ii][5] + bs[5];
        o1.z = acc[ii][6] + bs[6]; o1.w = acc[ii][7] + bs[7];
        ((float4*)orow)[0] = o0;
        ((float4*)orow)[1] = o1;
    }
}

// ---------------------------------------------------------------------------
// K2: persistent LSTM scan.  64 blocks x 512 threads; block b owns h-lanes
// {16b..16b+15} (64 gate rows).  Weights bf16 in LDS (128 KB/block), staged
// once with rotation c=(i+j)&15 baked in: per-step weight reads are
// lane-consecutive ds_read_b128 (conflict-free) and h reads hit 2-way max
// (free) — R7 verified (SQ_LDS_BANK_CONFLICT 1.9e9 -> 0).
// R7 lesson: 128 spinning blocks congest the coherence fabric (2 us/step
// exposed sync vs 0.3 us at 64 blocks in R5).  So: 64 participants + s_sleep
// backoff in the poll to cut spin duty cycle ~10x.
// Cross-block h exchange: 8-byte relaxed agent atomics {ver,bits}; no fences.
// 2-slot ring, max skew 1 step.
// ---------------------------------------------------------------------------
__device__ __forceinline__ float fsigmoid_(float x) {
    return 1.0f / (1.0f + __expf(-x));
}
__device__ __forceinline__ float ftanh_(float x) {
    x = fminf(fmaxf(x, -10.0f), 10.0f);
    const float e = __expf(2.0f * x);
    return (e - 1.0f) / (e + 1.0f);
}
__device__ __forceinline__ unsigned bf16rne_(float f) {   // finite inputs
    const unsigned u = __float_as_uint(f);
    return (u + 0x7FFFu + ((u >> 16) & 1u)) >> 16;
}
__device__ __forceinline__ float bf_lo_(unsigned u) {
    return __uint_as_float(u << 16);
}
__device__ __forceinline__ float bf_hi_(unsigned u) {
    return __uint_as_float(u & 0xFFFF0000u);
}

__global__ __launch_bounds__(NTHR, 1) void lstm_scan(
    const float* __restrict__ xg, const float* __restrict__ w_hh,
    const float* __restrict__ h0, const float* __restrict__ c0,
    unsigned long long* h_msg,           // [2][1024] {tag,bits}
    float* __restrict__ h_fin, float* __restrict__ c_fin)
{
    extern __shared__ char smem[];
    unsigned* w_lds   = (unsigned*)smem;            // 32768 u32 (64 rows bf16)
    float*    h_lds   = (float*)(smem + 131072);    // 1024 f32
    float*    xg_lds  = h_lds + H_DIM;              // 64
    float*    dot_lds = xg_lds + 64;                // 64

    const int tid  = threadIdx.x;
    const int b    = blockIdx.x;
    const int lane = tid & 63;
    const int wv   = tid >> 6;           // wave 0..7
    const int r    = tid >> 3;           // gate-row within block 0..63
    const int j    = tid & 7;            // k-slice (128 floats)
    const int g    = r >> 4;             // gate 0..3
    const int m    = r & 15;             // h-lane within block
    const int grow = g * 1024 + 16 * b + m;

    // ---- stage weights: fp32 global -> bf16 packed; slot i holds global
    // chunk c=(i+j)&15 (rotation baked into storage)
    {
        const float* wsrc = w_hh + (size_t)grow * 1024 + j * 128;
        uint4* wdst = (uint4*)w_lds + (size_t)wv * 1024 + lane;
        #pragma unroll
        for (int i = 0; i < 16; ++i) {
            const int c = (i + j) & 15;
            const float4 a = ((const float4*)(wsrc + c * 8))[0];
            const float4 d = ((const float4*)(wsrc + c * 8))[1];
            uint4 u;
            u.x = bf16rne_(a.x) | (bf16rne_(a.y) << 16);
            u.y = bf16rne_(a.z) | (bf16rne_(a.w) << 16);
            u.z = bf16rne_(d.x) | (bf16rne_(d.y) << 16);
            u.w = bf16rne_(d.z) | (bf16rne_(d.w) << 16);
            wdst[i * 64] = u;
        }
    }

    float c_reg = 0.0f;
    if (tid < 16) c_reg = c0[16 * b + tid];

    // h version 0 from h0
    ((float2*)h_lds)[tid] = ((const float2*)h0)[tid];

    // prefetch xg for t=0 (tid<64 owns (gate=tid>>4, lane m=tid&15))
    float xc = 0.0f;
    if (tid < 64)
        xc = xg[(size_t)(tid >> 4) * 1024 + 16 * b + (tid & 15)];
    __syncthreads();

    const uint4*  wrd = (const uint4*)w_lds + (size_t)wv * 1024 + lane;
    const float4* h4  = (const float4*)h_lds + j * 32;

    // prime the weight registers (reloaded each iter during the poll window)
    uint4 wreg[16];
    #pragma unroll
    for (int i = 0; i < 16; ++i) wreg[i] = wrd[i * 64];

    for (int t = 0; t < T_SEQ; ++t) {
        // stage this step's xg into LDS; issue next step's prefetch
        if (tid < 64) {
            xg_lds[tid] = xc;
            if (t < T_SEQ - 1)
                xc = xg[(size_t)(t + 1) * G4 + (tid >> 4) * 1024 + 16 * b + (tid & 15)];
        }

        // 128-MAC partial dot: bf16 weights (registers, loaded from LDS during
        // the previous poll window) x fp32 h (LDS, 2-way max = free)
        float acc = 0.0f;
        #pragma unroll
        for (int i = 0; i < 16; ++i) {
            const int c = (i + j) & 15;
            const uint4  u  = wreg[i];
            const float4 ha = h4[2 * c];
            const float4 hb = h4[2 * c + 1];
            acc = fmaf(bf_lo_(u.x), ha.x, acc);
            acc = fmaf(bf_hi_(u.x), ha.y, acc);
            acc = fmaf(bf_lo_(u.y), ha.z, acc);
            acc = fmaf(bf_hi_(u.y), ha.w, acc);
            acc = fmaf(bf_lo_(u.z), hb.x, acc);
            acc = fmaf(bf_hi_(u.z), hb.y, acc);
            acc = fmaf(bf_lo_(u.w), hb.z, acc);
            acc = fmaf(bf_hi_(u.w), hb.w, acc);
        }
        acc += __shfl_xor(acc, 1);
        acc += __shfl_xor(acc, 2);
        acc += __shfl_xor(acc, 4);
        if (j == 0) dot_lds[r] = acc;
        __syncthreads();

        // pointwise update + publish (16 threads; rest proceed to their polls)
        if (tid < 16) {
            const float gi = xg_lds[tid]      + dot_lds[tid];
            const float gf = xg_lds[16 + tid] + dot_lds[16 + tid];
            const float gg = xg_lds[32 + tid] + dot_lds[32 + tid];
            const float go = xg_lds[48 + tid] + dot_lds[48 + tid];
            const float ii = fsigmoid_(gi);
            const float ff = fsigmoid_(gf);
            const float gt = ftanh_(gg);
            const float oo = fsigmoid_(go);
            c_reg = ff * c_reg + ii * gt;
            const float hn = oo * ftanh_(c_reg);
            const unsigned long long msg =
                ((unsigned long long)(unsigned)(t + 1) << 32) | __float_as_uint(hn);
            __hip_atomic_store(&h_msg[(size_t)((t + 1) & 1) * H_DIM + 16 * b + tid],
                               msg, __ATOMIC_RELAXED, __HIP_MEMORY_SCOPE_AGENT);
            if (t == T_SEQ - 1) {
                h_fin[16 * b + tid] = hn;
                c_fin[16 * b + tid] = c_reg;
            }
        }

        // re-issue weight loads for next iteration; latency hides under poll
        #pragma unroll
        for (int i = 0; i < 16; ++i) wreg[i] = wrd[i * 64];

        // gather h version t+1: each thread polls only its own 2 messages;
        // s_sleep backoff keeps 64*512 spinners from congesting the fabric
        if (t < T_SEQ - 1) {
            const unsigned ver = (unsigned)(t + 1);
            const unsigned long long* src =
                h_msg + (size_t)(ver & 1) * H_DIM + 2 * tid;
            unsigned long long v0, v1;
            for (;;) {
                v0 = __hip_atomic_load(src + 0, __ATOMIC_RELAXED, __HIP_MEMORY_SCOPE_AGENT);
                v1 = __hip_atomic_load(src + 1, __ATOMIC_RELAXED, __HIP_MEMORY_SCOPE_AGENT);
                if (((unsigned)(v0 >> 32) == ver) & ((unsigned)(v1 >> 32) == ver))
                    break;
                __builtin_amdgcn_s_sleep(1);
            }
            float2 hv;
            hv.x = __uint_as_float((unsigned)v0);
            hv.y = __uint_as_float((unsigned)v1);
            ((float2*)h_lds)[tid] = hv;
            __syncthreads();
        }
    }
}

// ---------------------------------------------------------------------------
// K3: four 256x1024 mat-vec projections + bias.  One output per 32-lane group.
// ---------------------------------------------------------------------------
__global__ __launch_bounds__(256) void proj_kernel(
    const float* __restrict__ h_fin, const float* __restrict__ c_fin,
    const float* __restrict__ W_hm, const float* __restrict__ b_hm,
    const float* __restrict__ W_hv, const float* __restrict__ b_hv,
    const float* __restrict__ W_cm, const float* __restrict__ b_cm,
    const float* __restrict__ W_cv, const float* __restrict__ b_cv,
    float* __restrict__ out)
{
    const int tid = threadIdx.x;
    const int g32 = tid >> 5;
    const int j   = tid & 31;
    const int o   = blockIdx.x * 8 + g32;   // 0..1023
    const int mat = o >> 8;
    const int l   = o & 255;

    const float* W;  const float* bias;  const float* vec;
    if      (mat == 0) { W = W_hm; bias = b_hm; vec = h_fin; }
    else if (mat == 1) { W = W_hv; bias = b_hv; vec = h_fin; }
    else if (mat == 2) { W = W_cm; bias = b_cm; vec = c_fin; }
    else               { W = W_cv; bias = b_cv; vec = c_fin; }

    const float* wrow = W + (size_t)l * 1024;
    float acc = 0.0f;
    #pragma unroll
    for (int i = 0; i < 8; ++i) {
        const float4 wv = *(const float4*)(wrow + i * 128 + j * 4);
        const float4 xv = *(const float4*)(vec  + i * 128 + j * 4);
        acc += wv.x * xv.x + wv.y * xv.y + wv.z * xv.z + wv.w * xv.w;
    }
    acc += __shfl_xor(acc, 1);
    acc += __shfl_xor(acc, 2);
    acc += __shfl_xor(acc, 4);
    acc += __shfl_xor(acc, 8);
    acc += __shfl_xor(acc, 16);
    if (j == 0) out[o] = acc + bias[l];
}

// ---------------------------------------------------------------------------
extern "C" void kernel_launch(void* const* d_in, const int* in_sizes, int n_in,
                              void* d_out, int out_size, void* d_ws, size_t ws_size,
                              hipStream_t stream)
{
    const int*   tokens = (const int*)  d_in[0];
    const float* h0     = (const float*)d_in[1];
    const float* c0     = (const float*)d_in[2];
    const float* emb    = (const float*)d_in[3];
    const float* w_ih   = (const float*)d_in[4];
    const float* w_hh   = (const float*)d_in[5];
    const float* b_ih   = (const float*)d_in[6];
    const float* b_hh   = (const float*)d_in[7];
    const float* W_hm   = (const float*)d_in[8];
    const float* b_hm   = (const float*)d_in[9];
    const float* W_hv   = (const float*)d_in[10];
    const float* b_hv   = (const float*)d_in[11];
    const float* W_cm   = (const float*)d_in[12];
    const float* b_cm   = (const float*)d_in[13];
    const float* W_cv   = (const float*)d_in[14];
    const float* b_cv   = (const float*)d_in[15];
    float* out = (float*)d_out;

    char* ws = (char*)d_ws;
    float*              xg    = (float*)ws;            // T*4H fp32 = 64 MB
    size_t              off   = (size_t)T_SEQ * G4 * sizeof(float);
    unsigned long long* h_msg = (unsigned long long*)(ws + off);
    off += 2 * H_DIM * sizeof(unsigned long long);     // 16 KB
    float* h_fin = (float*)(ws + off); off += H_DIM * sizeof(float);
    float* c_fin = (float*)(ws + off); off += H_DIM * sizeof(float);

    // allow 132.6 KB dynamic LDS for the scan kernel (host attr, capture-safe)
    hipFuncSetAttribute((const void*)lstm_scan,
                        hipFuncAttributeMaxDynamicSharedMemorySize,
                        SCAN_LDS_BYTES);

    // clear stale tags (part of the captured graph => replay-safe)
    hipMemsetAsync(h_msg, 0xFF, 2 * H_DIM * sizeof(unsigned long long), stream);

    xg_gemm<<<dim3(32, 32), 256, 0, stream>>>(tokens, emb, w_ih, b_ih, b_hh, xg);
    lstm_scan<<<NBLK, NTHR, SCAN_LDS_BYTES, stream>>>(xg, w_hh, h0, c0, h_msg,
                                                      h_fin, c_fin);
    proj_kernel<<<128, 256, 0, stream>>>(h_fin, c_fin, W_hm, b_hm, W_hv, b_hv,
                                         W_cm, b_cm, W_cv, b_cv, out);
}